// Round 1
// 1298.900 us; speedup vs baseline: 1.2340x; 1.2340x over previous
//
#include <hip/hip_runtime.h>

// Problem: temporal warp-difference.
// x: (32,3,720,1280) f32, flow: (30,2,720,1280) f32
// out: (30,6,720,1280) f32
//   out[n, c  ] = x[n+1,c] - x[n+2, c, clip(round(h+flow[n,0])), clip(round(w+flow[n,1]))]
//   out[n, 3+c] = x[n+1,c] - x[n,   c, clip(round(h+flow[29-n,0])), clip(round(w+flow[29-n,1]))]
// Memory-bound: ~2.1 GB compulsory traffic -> ~335 us floor at 6.3 TB/s.
//
// R1: 2D tiling (16 rows x 64 px per block) + chunked XCD swizzle.
//   Gathers displace +-~16 px (flow ~ N(0,4)). The old 1D blocks (1024 px of
//   one row) had a 33-row gather footprint whose reuse depended on
//   adjacent-row blocks -- which round-robin onto DIFFERENT XCDs (private
//   L2s). Chunked swizzle gives each XCD a contiguous row/n range so the
//   rolling gather window stays L2/LLC-resident; 2D tiles shrink the
//   per-block footprint ~6.5x.

#define TT 32
#define CC 3
#define HH 720
#define WW 1280
#define NN (TT - 2)

// Tile geometry: 256 threads = 16 rows x 16 quads (64 px)
#define TILE_H   16
#define TILE_WQ  16
#define TILES_W  (WW / (TILE_WQ * 4))      // 20
#define TILES_H  (HH / TILE_H)             // 45
#define TILES_PER_N (TILES_W * TILES_H)    // 900
#define NWG      (NN * TILES_PER_N)        // 27000  (divisible by 8)
#define NXCD     8

__device__ __forceinline__ int clampi(int v, int lo, int hi) {
    return v < lo ? lo : (v > hi ? hi : v);
}

__global__ __launch_bounds__(256) void warp_diff_kernel(
    const float* __restrict__ x,
    const float* __restrict__ flow,
    float* __restrict__ out)
{
    // Chunked XCD swizzle: consecutive hardware blocks round-robin across
    // XCDs; this remap hands each XCD one contiguous chunk of the work
    // (27000 % 8 == 0 -> bijective).
    const int wid  = blockIdx.x;
    const int work = (wid % NXCD) * (NWG / NXCD) + wid / NXCD;

    const int tile = work % TILES_PER_N;
    const int n    = work / TILES_PER_N;
    const int tw   = tile % TILES_W;
    const int th   = tile / TILES_W;

    const int ty = threadIdx.x >> 4;   // 0..15 row within tile
    const int tx = threadIdx.x & 15;   // 0..15 quad within tile row

    const int h  = th * TILE_H + ty;
    const int w0 = (tw * TILE_WQ + tx) * 4;

    const size_t HW = (size_t)HH * WW;
    const size_t rowoff = (size_t)h * WW + w0;

    // flow loads (vectorized, coalesced per 16-lane row group)
    const float4 fdx = *(const float4*)(flow + ((size_t)n * 2 + 0) * HW + rowoff);
    const float4 fdy = *(const float4*)(flow + ((size_t)n * 2 + 1) * HW + rowoff);
    const float4 bdx = *(const float4*)(flow + ((size_t)(NN - 1 - n) * 2 + 0) * HW + rowoff);
    const float4 bdy = *(const float4*)(flow + ((size_t)(NN - 1 - n) * 2 + 1) * HW + rowoff);

    // round half-to-even (jnp.round semantics): rintf uses RNE -> matches.
    const float fh = (float)h;
    int gf[4], gb[4];
    {
        const float fdxv[4] = {fdx.x, fdx.y, fdx.z, fdx.w};
        const float fdyv[4] = {fdy.x, fdy.y, fdy.z, fdy.w};
        const float bdxv[4] = {bdx.x, bdx.y, bdx.z, bdx.w};
        const float bdyv[4] = {bdy.x, bdy.y, bdy.z, bdy.w};
#pragma unroll
        for (int j = 0; j < 4; ++j) {
            float fw = (float)(w0 + j);
            int ixf = clampi((int)rintf(fh + fdxv[j]), 0, HH - 1);
            int iyf = clampi((int)rintf(fw + fdyv[j]), 0, WW - 1);
            int ixb = clampi((int)rintf(fh + bdxv[j]), 0, HH - 1);
            int iyb = clampi((int)rintf(fw + bdyv[j]), 0, WW - 1);
            gf[j] = ixf * WW + iyf;    // fits in int: < 921600
            gb[j] = ixb * WW + iyb;
        }
    }

    const float* xc_base = x + ((size_t)(n + 1) * CC) * HW + rowoff;
    const float* xf_base = x + ((size_t)(n + 2) * CC) * HW;
    const float* xb_base = x + ((size_t)(n + 0) * CC) * HW;
    float* out_f = out + ((size_t)n * 6) * HW + rowoff;
    float* out_b = out_f + 3 * HW;

#pragma unroll
    for (int c = 0; c < CC; ++c) {
        const float4 vc = *(const float4*)(xc_base + (size_t)c * HW);
        const float* xf = xf_base + (size_t)c * HW;
        const float* xb = xb_base + (size_t)c * HW;

        float4 of, ob;
        of.x = vc.x - xf[gf[0]];
        of.y = vc.y - xf[gf[1]];
        of.z = vc.z - xf[gf[2]];
        of.w = vc.w - xf[gf[3]];
        ob.x = vc.x - xb[gb[0]];
        ob.y = vc.y - xb[gb[1]];
        ob.z = vc.z - xb[gb[2]];
        ob.w = vc.w - xb[gb[3]];

        *(float4*)(out_f + (size_t)c * HW) = of;
        *(float4*)(out_b + (size_t)c * HW) = ob;
    }
}

extern "C" void kernel_launch(void* const* d_in, const int* in_sizes, int n_in,
                              void* d_out, int out_size, void* d_ws, size_t ws_size,
                              hipStream_t stream) {
    const float* x    = (const float*)d_in[0];
    const float* flow = (const float*)d_in[1];
    float* out = (float*)d_out;

    warp_diff_kernel<<<NWG, 256, 0, stream>>>(x, flow, out);
}